// Round 3
// baseline (93.314 us; speedup 1.0000x reference)
//
#include <hip/hip_runtime.h>

#define BLOCK 256
#define GPB 16          // graphs owned per block

// Prefix kernel: bs[t] = lower_bound(batch, t*GPB), t in [0, nb]
__global__ __launch_bounds__(256) void find_starts(
    const int* __restrict__ batch, int n, int nb, int* __restrict__ bs)
{
    int t = blockIdx.x * blockDim.x + threadIdx.x;
    if (t > nb) return;
    int target = t * GPB;
    int lo = 0, hi = n;
    while (lo < hi) {
        int mid = (lo + hi) >> 1;
        if (batch[mid] < target) lo = mid + 1; else hi = mid;
    }
    bs[t] = lo;
}

__global__ __launch_bounds__(BLOCK) void e3nn_fused(
    const int* __restrict__ z, const float* __restrict__ pos,
    const int* __restrict__ batch,
    const float* __restrict__ embed,
    const float* __restrict__ lin_w, const float* __restrict__ lin_b,
    const float* __restrict__ tp1_w, const float* __restrict__ tp2_w,
    const float* __restrict__ tp3_w, const float* __restrict__ gate_w,
    const float* __restrict__ fc_w, const float* __restrict__ fc_b,
    const int* __restrict__ bs,
    float* __restrict__ out)
{
    __shared__ float acc[GPB * 3];

    const int tid = threadIdx.x;
    const int lane = tid & 63;
    const int b = blockIdx.x;
    const int g0 = b * GPB;

    const int sN = bs[b];
    const int eN = bs[b + 1];

    if (tid < GPB * 3) acc[tid] = 0.0f;
    __syncthreads();

    // Wigner / path-weight constants
    const float C01 = 0.57735026918962576f;   // 1/sqrt(3)
    const float C11 = 0.40824829046386302f;   // 1/sqrt(6)
    const float PW2 = 1.2247448713915890f;    // sqrt(1.5)

    // cross(v,v) == 0 -> layer 1 collapses to (t0+t1)*C01 * s * v
    const float k1 = (tp1_w[0] + tp1_w[1]) * C01;
    float la[3], lbc[3];
    la[0] = PW2 * tp2_w[0] * C01;  lbc[0] = PW2 * tp2_w[1] * C11;
    la[1] = PW2 * tp3_w[0] * C01;  lbc[1] = PW2 * tp3_w[1] * C11;
    la[2] = PW2 * gate_w[0] * C01; lbc[2] = PW2 * gate_w[1] * C11;

    float lw[9], fw[9], lbv[3], fbv[3];
#pragma unroll
    for (int i = 0; i < 9; ++i) { lw[i] = lin_w[i]; fw[i] = fc_w[i]; }
#pragma unroll
    for (int i = 0; i < 3; ++i) { lbv[i] = lin_b[i]; fbv[i] = fc_b[i]; }

    // contiguous per-thread partition keeps keys sorted across lanes
    const int range = eN - sN;
    const int c = (range + BLOCK - 1) / BLOCK;
    const int start = sN + tid * c;
    const int end   = min(start + c, eN);

    float rx = 0.f, ry = 0.f, rz = 0.f;
    int rb = -1;

#pragma unroll 2
    for (int i = start; i < end; ++i) {
        float se = embed[z[i]];
        float px = pos[3*i], py = pos[3*i+1], pz = pos[3*i+2];
        int bidx = batch[i];

        float vx = lw[0]*px + lw[1]*py + lw[2]*pz + lbv[0];
        float vy = lw[3]*px + lw[4]*py + lw[5]*pz + lbv[1];
        float vz = lw[6]*px + lw[7]*py + lw[8]*pz + lbv[2];

        float ks = k1 * se;
        float ox = ks * vx, oy = ks * vy, oz = ks * vz;

#pragma unroll
        for (int l = 0; l < 3; ++l) {
            float cx = oy*vz - oz*vy;
            float cy = oz*vx - ox*vz;
            float cz = ox*vy - oy*vx;
            float as_ = la[l] * se;
            ox = as_*ox + lbc[l]*cx;
            oy = as_*oy + lbc[l]*cy;
            oz = as_*oz + lbc[l]*cz;
        }

        float yx = fw[0]*ox + fw[1]*oy + fw[2]*oz + fbv[0];
        float yy = fw[3]*ox + fw[4]*oy + fw[5]*oz + fbv[1];
        float yz = fw[6]*ox + fw[7]*oy + fw[8]*oz + fbv[2];

        if (bidx == rb) { rx += yx; ry += yy; rz += yz; }
        else {
            if (rb >= 0) {  // spill earlier run (always owned by this block)
                int e0 = (rb - g0) * 3;
                atomicAdd(&acc[e0+0], rx);
                atomicAdd(&acc[e0+1], ry);
                atomicAdd(&acc[e0+2], rz);
            }
            rb = bidx; rx = yx; ry = yy; rz = yz;
        }
    }

    // wave-level segmented reduction of each lane's LAST run (keys sorted
    // across lanes; trailing idle lanes have rb=-1 and never merge)
#pragma unroll
    for (int off = 1; off < 64; off <<= 1) {
        int   ob = __shfl_down(rb, off);
        float ox = __shfl_down(rx, off);
        float oy = __shfl_down(ry, off);
        float oz = __shfl_down(rz, off);
        if ((lane + off) < 64 && ob == rb) { rx += ox; ry += oy; rz += oz; }
    }
    int pb = __shfl_up(rb, 1);
    bool head = (lane == 0) || (pb != rb);
    if (rb >= 0 && head) {
        int e0 = (rb - g0) * 3;
        atomicAdd(&acc[e0+0], rx);
        atomicAdd(&acc[e0+1], ry);
        atomicAdd(&acc[e0+2], rz);
    }

    __syncthreads();

    // exclusive ownership: plain coalesced stores, covers empty graphs too
    if (tid < GPB * 3) out[g0 * 3 + tid] = acc[tid];
}

extern "C" void kernel_launch(void* const* d_in, const int* in_sizes, int n_in,
                              void* d_out, int out_size, void* d_ws, size_t ws_size,
                              hipStream_t stream) {
    const int*   z     = (const int*)  d_in[0];
    const float* pos   = (const float*)d_in[1];
    const int*   batch = (const int*)  d_in[2];
    const float* embed = (const float*)d_in[3];
    const float* lin_w = (const float*)d_in[4];
    const float* lin_b = (const float*)d_in[5];
    const float* tp1_w = (const float*)d_in[6];
    const float* tp2_w = (const float*)d_in[7];
    const float* tp3_w = (const float*)d_in[8];
    const float* gate_w= (const float*)d_in[9];
    const float* fc_w  = (const float*)d_in[10];
    const float* fc_b  = (const float*)d_in[11];
    float* out = (float*)d_out;

    int n = in_sizes[0];
    int num_graphs = out_size / 3;
    int nb = (num_graphs + GPB - 1) / GPB;   // blocks / ownership ranges

    int* bs = (int*)d_ws;                    // (nb+1) ints of scratch

    find_starts<<<(nb + 1 + 255) / 256, 256, 0, stream>>>(batch, n, nb, bs);

    e3nn_fused<<<nb, BLOCK, 0, stream>>>(
        z, pos, batch, embed, lin_w, lin_b,
        tp1_w, tp2_w, tp3_w, gate_w, fc_w, fc_b, bs, out);
}

// Round 4
// 39.442 us; speedup vs baseline: 2.3659x; 2.3659x over previous
//
#include <hip/hip_runtime.h>

#define BLOCK 256
#define GPB 16          // graphs owned per block

// bs[t] = lower_bound(batch, t*GPB), t in [0, nb]
__global__ __launch_bounds__(256) void find_starts(
    const int* __restrict__ batch, int n, int nb, int* __restrict__ bs)
{
    int t = blockIdx.x * blockDim.x + threadIdx.x;
    if (t > nb) return;
    int target = t * GPB;
    int lo = 0, hi = n;
    while (lo < hi) {
        int mid = (lo + hi) >> 1;
        if (batch[mid] < target) lo = mid + 1; else hi = mid;
    }
    bs[t] = lo;
}

__global__ __launch_bounds__(BLOCK) void e3nn_fused(
    const int* __restrict__ z, const float* __restrict__ pos,
    const int* __restrict__ batch,
    const float* __restrict__ embed,
    const float* __restrict__ lin_w, const float* __restrict__ lin_b,
    const float* __restrict__ tp1_w, const float* __restrict__ tp2_w,
    const float* __restrict__ tp3_w, const float* __restrict__ gate_w,
    const float* __restrict__ fc_w, const float* __restrict__ fc_b,
    const int* __restrict__ bs,
    float* __restrict__ out)
{
    __shared__ float acc[GPB * 3];

    const int tid = threadIdx.x;
    const int lane = tid & 63;
    const int b = blockIdx.x;
    const int g0 = b * GPB;

    const int sN = bs[b];
    const int eN = bs[b + 1];

    if (tid < GPB * 3) acc[tid] = 0.0f;
    __syncthreads();

    // Wigner / path-weight constants
    const float C01 = 0.57735026918962576f;   // 1/sqrt(3)
    const float C11 = 0.40824829046386302f;   // 1/sqrt(6)
    const float PW2 = 1.2247448713915890f;    // sqrt(1.5)

    // cross(v,v) == 0 -> layer 1 collapses to (t0+t1)*C01 * s * v
    const float k1 = (tp1_w[0] + tp1_w[1]) * C01;
    float la[3], lbc[3];
    la[0] = PW2 * tp2_w[0] * C01;  lbc[0] = PW2 * tp2_w[1] * C11;
    la[1] = PW2 * tp3_w[0] * C01;  lbc[1] = PW2 * tp3_w[1] * C11;
    la[2] = PW2 * gate_w[0] * C01; lbc[2] = PW2 * gate_w[1] * C11;

    float lw[9], fw[9], lbv[3], fbv[3];
#pragma unroll
    for (int i = 0; i < 9; ++i) { lw[i] = lin_w[i]; fw[i] = fc_w[i]; }
#pragma unroll
    for (int i = 0; i < 3; ++i) { lbv[i] = lin_b[i]; fbv[i] = fc_b[i]; }

    const int range = eN - sN;
    const int iters = (range + BLOCK - 1) / BLOCK;   // block-uniform

    for (int j = 0; j < iters; ++j) {
        // wave covers 64 CONSECUTIVE nodes -> coalesced loads, sorted keys
        int i = sN + j * BLOCK + tid;
        bool act = i < eN;
        int ii = act ? i : (eN - 1);     // clamp for safe loads (range>0 here)

        int key = act ? batch[ii] : -1;
        float se = embed[z[ii]];
        float px = pos[3*ii], py = pos[3*ii+1], pz = pos[3*ii+2];

        float vx = lw[0]*px + lw[1]*py + lw[2]*pz + lbv[0];
        float vy = lw[3]*px + lw[4]*py + lw[5]*pz + lbv[1];
        float vz = lw[6]*px + lw[7]*py + lw[8]*pz + lbv[2];

        float ks = k1 * se;
        float ox = ks * vx, oy = ks * vy, oz = ks * vz;

#pragma unroll
        for (int l = 0; l < 3; ++l) {
            float cx = oy*vz - oz*vy;
            float cy = oz*vx - ox*vz;
            float cz = ox*vy - oy*vx;
            float as_ = la[l] * se;
            ox = as_*ox + lbc[l]*cx;
            oy = as_*oy + lbc[l]*cy;
            oz = as_*oz + lbc[l]*cz;
        }

        float yx = fw[0]*ox + fw[1]*oy + fw[2]*oz + fbv[0];
        float yy = fw[3]*ox + fw[4]*oy + fw[5]*oz + fbv[1];
        float yz = fw[6]*ox + fw[7]*oy + fw[8]*oz + fbv[2];

        // segmented suffix reduce over the wave (keys non-decreasing;
        // inactive high lanes have key=-1 and never merge into active runs)
#pragma unroll
        for (int off = 1; off < 64; off <<= 1) {
            int   ob = __shfl_down(key, off);
            float qx = __shfl_down(yx, off);
            float qy = __shfl_down(yy, off);
            float qz = __shfl_down(yz, off);
            if ((lane + off) < 64 && ob == key) { yx += qx; yy += qy; yz += qz; }
        }
        int pk = __shfl_up(key, 1);
        if (act && (lane == 0 || pk != key)) {
            int e0 = (key - g0) * 3;     // key guaranteed in [g0, g0+GPB)
            atomicAdd(&acc[e0+0], yx);
            atomicAdd(&acc[e0+1], yy);
            atomicAdd(&acc[e0+2], yz);
        }
    }

    __syncthreads();

    // exclusive ownership: plain coalesced stores, covers empty graphs too
    if (tid < GPB * 3) out[g0 * 3 + tid] = acc[tid];
}

extern "C" void kernel_launch(void* const* d_in, const int* in_sizes, int n_in,
                              void* d_out, int out_size, void* d_ws, size_t ws_size,
                              hipStream_t stream) {
    const int*   z     = (const int*)  d_in[0];
    const float* pos   = (const float*)d_in[1];
    const int*   batch = (const int*)  d_in[2];
    const float* embed = (const float*)d_in[3];
    const float* lin_w = (const float*)d_in[4];
    const float* lin_b = (const float*)d_in[5];
    const float* tp1_w = (const float*)d_in[6];
    const float* tp2_w = (const float*)d_in[7];
    const float* tp3_w = (const float*)d_in[8];
    const float* gate_w= (const float*)d_in[9];
    const float* fc_w  = (const float*)d_in[10];
    const float* fc_b  = (const float*)d_in[11];
    float* out = (float*)d_out;

    int n = in_sizes[0];
    int num_graphs = out_size / 3;
    int nb = (num_graphs + GPB - 1) / GPB;   // 2048 ownership blocks

    int* bs = (int*)d_ws;                    // (nb+1) ints of scratch

    find_starts<<<(nb + 1 + 255) / 256, 256, 0, stream>>>(batch, n, nb, bs);

    e3nn_fused<<<nb, BLOCK, 0, stream>>>(
        z, pos, batch, embed, lin_w, lin_b,
        tp1_w, tp2_w, tp3_w, gate_w, fc_w, fc_b, bs, out);
}

// Round 6
// 31.043 us; speedup vs baseline: 3.0060x; 1.2706x over previous
//
#include <hip/hip_runtime.h>

#define BLOCK 256
#define NPT 8                     // nodes per thread
#define CHUNK (BLOCK * NPT)       // 2048 nodes per block

// out_size = 98304 floats = 24576 float4 exactly
__global__ __launch_bounds__(256) void zero_out(float4* __restrict__ out, int n4) {
    int i = blockIdx.x * blockDim.x + threadIdx.x;
    if (i < n4) out[i] = make_float4(0.f, 0.f, 0.f, 0.f);
}

// min 4 waves/EU -> VGPR cap 128: give the compiler room to interleave the
// 8 independent per-node dependency chains (VGPR=28 at default bounds
// serialized them -> 20% VALUBusy, latency-bound body)
__global__ __launch_bounds__(BLOCK, 4) void e3nn_fused(
    const int* __restrict__ z, const float* __restrict__ pos,
    const int* __restrict__ batch,
    const float* __restrict__ embed,
    const float* __restrict__ lin_w, const float* __restrict__ lin_b,
    const float* __restrict__ tp1_w, const float* __restrict__ tp2_w,
    const float* __restrict__ tp3_w, const float* __restrict__ gate_w,
    const float* __restrict__ fc_w, const float* __restrict__ fc_b,
    float* __restrict__ out, int n)
{
    const int tid = threadIdx.x;
    const int lane = tid & 63;
    const long long i0 = (long long)blockIdx.x * CHUNK + (long long)tid * NPT;

    float px[NPT], py[NPT], pz[NPT];
    int zi[NPT], bi[NPT];

    if (i0 + NPT <= (long long)n) {
        const float4* p4 = (const float4*)(pos + i0 * 3);
        float4 q0 = p4[0], q1 = p4[1], q2 = p4[2], q3 = p4[3], q4 = p4[4], q5 = p4[5];
        px[0]=q0.x; py[0]=q0.y; pz[0]=q0.z;
        px[1]=q0.w; py[1]=q1.x; pz[1]=q1.y;
        px[2]=q1.z; py[2]=q1.w; pz[2]=q2.x;
        px[3]=q2.y; py[3]=q2.z; pz[3]=q2.w;
        px[4]=q3.x; py[4]=q3.y; pz[4]=q3.z;
        px[5]=q3.w; py[5]=q4.x; pz[5]=q4.y;
        px[6]=q4.z; py[6]=q4.w; pz[6]=q5.x;
        px[7]=q5.y; py[7]=q5.z; pz[7]=q5.w;
        int4 za = *(const int4*)(z + i0), zb = *(const int4*)(z + i0 + 4);
        zi[0]=za.x; zi[1]=za.y; zi[2]=za.z; zi[3]=za.w;
        zi[4]=zb.x; zi[5]=zb.y; zi[6]=zb.z; zi[7]=zb.w;
        int4 ba = *(const int4*)(batch + i0), bb = *(const int4*)(batch + i0 + 4);
        bi[0]=ba.x; bi[1]=ba.y; bi[2]=ba.z; bi[3]=ba.w;
        bi[4]=bb.x; bi[5]=bb.y; bi[6]=bb.z; bi[7]=bb.w;
    } else {
#pragma unroll
        for (int k = 0; k < NPT; ++k) {
            long long i = i0 + k;
            if (i < (long long)n) {
                px[k]=pos[i*3]; py[k]=pos[i*3+1]; pz[k]=pos[i*3+2];
                zi[k]=z[i]; bi[k]=batch[i];
            } else { px[k]=0.f; py[k]=0.f; pz[k]=0.f; zi[k]=0; bi[k]=-1; }
        }
    }

    // Wigner / path-weight constants
    const float C01 = 0.57735026918962576f;   // 1/sqrt(3)
    const float C11 = 0.40824829046386302f;   // 1/sqrt(6)
    const float PW2 = 1.2247448713915890f;    // sqrt(1.5)

    // cross(v,v) == 0 -> layer 1 collapses to (t0+t1)*C01 * s * v
    const float k1 = (tp1_w[0] + tp1_w[1]) * C01;
    float la[3], lbc[3];
    la[0] = PW2 * tp2_w[0] * C01;  lbc[0] = PW2 * tp2_w[1] * C11;
    la[1] = PW2 * tp3_w[0] * C01;  lbc[1] = PW2 * tp3_w[1] * C11;
    la[2] = PW2 * gate_w[0] * C01; lbc[2] = PW2 * gate_w[1] * C11;

    float lw[9], fw[9], lbv[3], fbv[3];
#pragma unroll
    for (int i = 0; i < 9; ++i) { lw[i] = lin_w[i]; fw[i] = fc_w[i]; }
#pragma unroll
    for (int i = 0; i < 3; ++i) { lbv[i] = lin_b[i]; fbv[i] = fc_b[i]; }

    // per-thread run-length compression over sorted batch ids
    float rx = 0.f, ry = 0.f, rz = 0.f;
    int rb = -1;

#pragma unroll
    for (int k = 0; k < NPT; ++k) {
        if (bi[k] < 0) continue;
        float s  = embed[zi[k]];
        float vx = lw[0]*px[k] + lw[1]*py[k] + lw[2]*pz[k] + lbv[0];
        float vy = lw[3]*px[k] + lw[4]*py[k] + lw[5]*pz[k] + lbv[1];
        float vz = lw[6]*px[k] + lw[7]*py[k] + lw[8]*pz[k] + lbv[2];

        float ks = k1 * s;
        float ox = ks * vx, oy = ks * vy, oz = ks * vz;

#pragma unroll
        for (int l = 0; l < 3; ++l) {
            float cx = oy*vz - oz*vy;
            float cy = oz*vx - ox*vz;
            float cz = ox*vy - oy*vx;
            float as_ = la[l] * s;
            ox = as_*ox + lbc[l]*cx;
            oy = as_*oy + lbc[l]*cy;
            oz = as_*oz + lbc[l]*cz;
        }

        float yx = fw[0]*ox + fw[1]*oy + fw[2]*oz + fbv[0];
        float yy = fw[3]*ox + fw[4]*oy + fw[5]*oz + fbv[1];
        float yz = fw[6]*ox + fw[7]*oy + fw[8]*oz + fbv[2];

        if (bi[k] == rb) { rx += yx; ry += yy; rz += yz; }
        else {
            if (rb >= 0) {  // earlier run in this lane (rare: boundary inside lane)
                atomicAdd(&out[(long long)rb*3+0], rx);
                atomicAdd(&out[(long long)rb*3+1], ry);
                atomicAdd(&out[(long long)rb*3+2], rz);
            }
            rb = bi[k]; rx = yx; ry = yy; rz = yz;
        }
    }

    // wave-level segmented suffix reduction over each lane's LAST run.
#pragma unroll
    for (int off = 1; off < 64; off <<= 1) {
        int   ob = __shfl_down(rb, off);
        float ox = __shfl_down(rx, off);
        float oy = __shfl_down(ry, off);
        float oz = __shfl_down(rz, off);
        if ((lane + off) < 64 && ob == rb) { rx += ox; ry += oy; rz += oz; }
    }
    int pb = __shfl_up(rb, 1);
    bool head = (lane == 0) || (pb != rb);
    if (rb >= 0 && head) {
        atomicAdd(&out[(long long)rb*3+0], rx);
        atomicAdd(&out[(long long)rb*3+1], ry);
        atomicAdd(&out[(long long)rb*3+2], rz);
    }
}

extern "C" void kernel_launch(void* const* d_in, const int* in_sizes, int n_in,
                              void* d_out, int out_size, void* d_ws, size_t ws_size,
                              hipStream_t stream) {
    const int*   z     = (const int*)  d_in[0];
    const float* pos   = (const float*)d_in[1];
    const int*   batch = (const int*)  d_in[2];
    const float* embed = (const float*)d_in[3];
    const float* lin_w = (const float*)d_in[4];
    const float* lin_b = (const float*)d_in[5];
    const float* tp1_w = (const float*)d_in[6];
    const float* tp2_w = (const float*)d_in[7];
    const float* tp3_w = (const float*)d_in[8];
    const float* gate_w= (const float*)d_in[9];
    const float* fc_w  = (const float*)d_in[10];
    const float* fc_b  = (const float*)d_in[11];
    float* out = (float*)d_out;

    int n = in_sizes[0];

    // zero the accumulator target ourselves (hipMemsetAsync's fillBuffer
    // path showed a ~40us anomaly in profiles; 24576 float4 = out_size exactly)
    int n4 = out_size / 4;
    zero_out<<<(n4 + 255) / 256, 256, 0, stream>>>((float4*)out, n4);

    int nblocks = (n + CHUNK - 1) / CHUNK;
    e3nn_fused<<<nblocks, BLOCK, 0, stream>>>(
        z, pos, batch, embed, lin_w, lin_b,
        tp1_w, tp2_w, tp3_w, gate_w, fc_w, fc_b, out, n);
}

// Round 7
// 29.324 us; speedup vs baseline: 3.1821x; 1.0586x over previous
//
#include <hip/hip_runtime.h>

#define BLOCK 256
#define NPT 8                     // nodes per thread
#define CHUNK (BLOCK * NPT)       // 2048 nodes per block

__global__ __launch_bounds__(256) void zero_out(float4* __restrict__ out, int n4) {
    int i = blockIdx.x * blockDim.x + threadIdx.x;
    if (i < n4) out[i] = make_float4(0.f, 0.f, 0.f, 0.f);
}

// Algebraic collapse: out1 = k1*s*v is parallel to v, so every later
// cross(out, v) == 0 (to fp roundoff, matching the reference's own ~0 cross
// terms). The full model reduces to y = (C*s^4) * (W@p + u) + fc_b with
// W = fc_w@lin_w, u = fc_w@lin_b, C = k1*la0*la1*la2.
__global__ __launch_bounds__(BLOCK, 4) void e3nn_fused(
    const int* __restrict__ z, const float* __restrict__ pos,
    const int* __restrict__ batch,
    const float* __restrict__ embed,
    const float* __restrict__ lin_w, const float* __restrict__ lin_b,
    const float* __restrict__ tp1_w, const float* __restrict__ tp2_w,
    const float* __restrict__ tp3_w, const float* __restrict__ gate_w,
    const float* __restrict__ fc_w, const float* __restrict__ fc_b,
    float* __restrict__ out, int n)
{
    const int tid = threadIdx.x;
    const int lane = tid & 63;
    const long long i0 = (long long)blockIdx.x * CHUNK + (long long)tid * NPT;

    float px[NPT], py[NPT], pz[NPT];
    int zi[NPT], bi[NPT];

    if (i0 + NPT <= (long long)n) {
        const float4* p4 = (const float4*)(pos + i0 * 3);
        float4 q0 = p4[0], q1 = p4[1], q2 = p4[2], q3 = p4[3], q4 = p4[4], q5 = p4[5];
        px[0]=q0.x; py[0]=q0.y; pz[0]=q0.z;
        px[1]=q0.w; py[1]=q1.x; pz[1]=q1.y;
        px[2]=q1.z; py[2]=q1.w; pz[2]=q2.x;
        px[3]=q2.y; py[3]=q2.z; pz[3]=q2.w;
        px[4]=q3.x; py[4]=q3.y; pz[4]=q3.z;
        px[5]=q3.w; py[5]=q4.x; pz[5]=q4.y;
        px[6]=q4.z; py[6]=q4.w; pz[6]=q5.x;
        px[7]=q5.y; py[7]=q5.z; pz[7]=q5.w;
        int4 za = *(const int4*)(z + i0), zb = *(const int4*)(z + i0 + 4);
        zi[0]=za.x; zi[1]=za.y; zi[2]=za.z; zi[3]=za.w;
        zi[4]=zb.x; zi[5]=zb.y; zi[6]=zb.z; zi[7]=zb.w;
        int4 ba = *(const int4*)(batch + i0), bb = *(const int4*)(batch + i0 + 4);
        bi[0]=ba.x; bi[1]=ba.y; bi[2]=ba.z; bi[3]=ba.w;
        bi[4]=bb.x; bi[5]=bb.y; bi[6]=bb.z; bi[7]=bb.w;
    } else {
#pragma unroll
        for (int k = 0; k < NPT; ++k) {
            long long i = i0 + k;
            if (i < (long long)n) {
                px[k]=pos[i*3]; py[k]=pos[i*3+1]; pz[k]=pos[i*3+2];
                zi[k]=z[i]; bi[k]=batch[i];
            } else { px[k]=0.f; py[k]=0.f; pz[k]=0.f; zi[k]=0; bi[k]=-1; }
        }
    }

    // constants / collapsed weights
    const float C01 = 0.57735026918962576f;   // 1/sqrt(3)
    const float PW2 = 1.2247448713915890f;    // sqrt(1.5)

    const float k1  = (tp1_w[0] + tp1_w[1]) * C01;
    const float la0 = PW2 * tp2_w[0] * C01;
    const float la1 = PW2 * tp3_w[0] * C01;
    const float la2 = PW2 * gate_w[0] * C01;
    const float C   = k1 * la0 * la1 * la2;

    float lw[9], fw[9], lbv[3], fbv[3];
#pragma unroll
    for (int i = 0; i < 9; ++i) { lw[i] = lin_w[i]; fw[i] = fc_w[i]; }
#pragma unroll
    for (int i = 0; i < 3; ++i) { lbv[i] = lin_b[i]; fbv[i] = fc_b[i]; }

    // W = fc_w @ lin_w ; u = fc_w @ lin_b
    float W[9], u[3];
#pragma unroll
    for (int r = 0; r < 3; ++r) {
#pragma unroll
        for (int cc = 0; cc < 3; ++cc)
            W[r*3+cc] = fw[r*3+0]*lw[0*3+cc] + fw[r*3+1]*lw[1*3+cc] + fw[r*3+2]*lw[2*3+cc];
        u[r] = fw[r*3+0]*lbv[0] + fw[r*3+1]*lbv[1] + fw[r*3+2]*lbv[2];
    }

    // per-thread run-length compression over sorted batch ids
    float rx = 0.f, ry = 0.f, rz = 0.f;
    int rb = -1;

#pragma unroll
    for (int k = 0; k < NPT; ++k) {
        if (bi[k] < 0) continue;
        float s  = embed[zi[k]];
        float s2 = s * s;
        float t  = C * (s2 * s2);          // C * s^4

        float gx = W[0]*px[k] + W[1]*py[k] + W[2]*pz[k] + u[0];
        float gy = W[3]*px[k] + W[4]*py[k] + W[5]*pz[k] + u[1];
        float gz = W[6]*px[k] + W[7]*py[k] + W[8]*pz[k] + u[2];

        float yx = t * gx + fbv[0];
        float yy = t * gy + fbv[1];
        float yz = t * gz + fbv[2];

        if (bi[k] == rb) { rx += yx; ry += yy; rz += yz; }
        else {
            if (rb >= 0) {  // earlier run in this lane (boundary inside lane)
                atomicAdd(&out[(long long)rb*3+0], rx);
                atomicAdd(&out[(long long)rb*3+1], ry);
                atomicAdd(&out[(long long)rb*3+2], rz);
            }
            rb = bi[k]; rx = yx; ry = yy; rz = yz;
        }
    }

    // wave-level segmented suffix reduction over each lane's LAST run
#pragma unroll
    for (int off = 1; off < 64; off <<= 1) {
        int   ob = __shfl_down(rb, off);
        float ox = __shfl_down(rx, off);
        float oy = __shfl_down(ry, off);
        float oz = __shfl_down(rz, off);
        if ((lane + off) < 64 && ob == rb) { rx += ox; ry += oy; rz += oz; }
    }
    int pb = __shfl_up(rb, 1);
    bool head = (lane == 0) || (pb != rb);
    if (rb >= 0 && head) {
        atomicAdd(&out[(long long)rb*3+0], rx);
        atomicAdd(&out[(long long)rb*3+1], ry);
        atomicAdd(&out[(long long)rb*3+2], rz);
    }
}

extern "C" void kernel_launch(void* const* d_in, const int* in_sizes, int n_in,
                              void* d_out, int out_size, void* d_ws, size_t ws_size,
                              hipStream_t stream) {
    const int*   z     = (const int*)  d_in[0];
    const float* pos   = (const float*)d_in[1];
    const int*   batch = (const int*)  d_in[2];
    const float* embed = (const float*)d_in[3];
    const float* lin_w = (const float*)d_in[4];
    const float* lin_b = (const float*)d_in[5];
    const float* tp1_w = (const float*)d_in[6];
    const float* tp2_w = (const float*)d_in[7];
    const float* tp3_w = (const float*)d_in[8];
    const float* gate_w= (const float*)d_in[9];
    const float* fc_w  = (const float*)d_in[10];
    const float* fc_b  = (const float*)d_in[11];
    float* out = (float*)d_out;

    int n = in_sizes[0];

    int n4 = out_size / 4;   // 98304 floats = 24576 float4 exactly
    zero_out<<<(n4 + 255) / 256, 256, 0, stream>>>((float4*)out, n4);

    int nblocks = (n + CHUNK - 1) / CHUNK;
    e3nn_fused<<<nblocks, BLOCK, 0, stream>>>(
        z, pos, batch, embed, lin_w, lin_b,
        tp1_w, tp2_w, tp3_w, gate_w, fc_w, fc_b, out, n);
}